// Round 15
// baseline (238.668 us; speedup 1.0000x reference)
//
#include <hip/hip_runtime.h>
#include <hip/hip_bf16.h>
#include <stdint.h>

typedef __attribute__((ext_vector_type(4))) float f32x4;
typedef __attribute__((ext_vector_type(8))) short s16x8;
typedef __attribute__((ext_vector_type(4))) short s16x4;
typedef __attribute__((ext_vector_type(4))) int i32x4;

typedef const __attribute__((address_space(1))) unsigned glb_u32;
typedef __attribute__((address_space(3))) unsigned lds_u32;

#define DEVI __device__ __forceinline__

DEVI short f2b(float f) {
    union { float f; unsigned u; } v; v.f = f;
    unsigned r = v.u + 0x7fffu + ((v.u >> 16) & 1u);
    return (short)(r >> 16);
}

DEVI float vexp2(float x) {           // raw v_exp_f32: 2^x
    float r;
    asm("v_exp_f32 %0, %1" : "=v"(r) : "v"(x));
    return r;
}

DEVI unsigned cvtpk(float lo, float hi) {   // d.bf16[0]=lo, d.bf16[1]=hi (RNE)
    unsigned d;
    asm("v_cvt_pk_bf16_f32 %0, %1, %2" : "=v"(d) : "v"(lo), "v"(hi));
    return d;
}

DEVI s16x8 pack8(const f32x4& a, const f32x4& b) {  // v[0..3]=a, v[4..7]=b
    union { unsigned u[4]; s16x8 v; } w;
    w.u[0] = cvtpk(a[0], a[1]);
    w.u[1] = cvtpk(a[2], a[3]);
    w.u[2] = cvtpk(b[0], b[1]);
    w.u[3] = cvtpk(b[2], b[3]);
    return w.v;
}

// exp2-domain constants. qr is pre-scaled by QSCL in its GEMM epilogue, so
// QK^T MFMA output is already score*log2(e); softmax needs NO max-shift.
#define QSCL 0.18033688011112042f      /* 0.125 * log2(e) */
#define MASKV -1.4426950408889634e9f   /* -1e9 * log2(e); exp2 -> exact 0 */

// ---------------- fused convert: v, k (8M elems each) + 5 weights -> bf16 ----
struct Ptr7 { const float* p[7]; };   // v, k, Wv, Wk, Wq, Wr, Wm

__global__ __launch_bounds__(256) void cvt_all(Ptr7 t, short* __restrict__ vb,
                                               short* __restrict__ kb,
                                               short* __restrict__ Wb) {
    int bid = blockIdx.x;             // 0..10751
    const float* s; short* d; int off;
    if (bid < 4096)      { s = t.p[0]; d = vb; off = bid; }
    else if (bid < 8192) { s = t.p[1]; d = kb; off = bid - 4096; }
    else {
        int w = (bid - 8192) >> 9;
        s = t.p[2 + w]; d = Wb + (size_t)w * 1048576u; off = (bid - 8192) & 511;
    }
    int i = (off * 256 + threadIdx.x) * 8;
    f32x4 a = *(const f32x4*)(s + i);
    f32x4 b = *(const f32x4*)(s + i + 4);
    *(s16x8*)(d + i) = pack8(a, b);
}

// ---------------- NT GEMM body (round-14 verified, shared) -------------------
// Swizzled LDS layout (T2): LDS[row][slot] holds K-quarter slot ^ ((row>>1)&3);
// reads use slot = g ^ ((r>>1)&3) -> 2-way max (free).
// bf16 path: T4-lite (3 buf, counted vmcnt(4), raw barrier; round-12 ledger).
// AF32 path: f32 reg-staged + cvt_pk, 2-buffer syncthreads loop (rounds 8/9/14).
// OUTMODE: 0 bf16 row-major | 1 f32 row-major | 2 bf16 per-head-transposed
//          [b][h][d][pos], pos = pi(tok) | 3 bf16 row-major scaled QSCL.
// TWO: C = A0*W0^T + A1*W1^T + b0 + b1 (K=2*1024).
template<int AF32, int OUTMODE, int TWO>
DEVI void gemm_body(int logical,
                    const void* A0_, const void* A1_,
                    const short* W0, const short* W1,
                    const float* b0, const float* b1,
                    void* C_, short* As, short* Ws)
{
    constexpr int K = 1024, N = 1024;
    const int tid = threadIdx.x;
    const int lane = tid & 63, wid = tid >> 6;
    const int wm = wid >> 1, wn = wid & 1;
    const int r = lane & 15, g = lane >> 4;
    const int n0 = (logical & 7) * 128, m0 = (logical >> 3) * 128;

    // ---- bf16 path staging (T4-lite): LDS linear, source quarter swizzled
    const int arow = lane >> 2;
    const int lq8 = ((lane & 3) ^ ((lane >> 3) & 3)) * 8;
    auto stage = [&](int buf, int kt) {
        int kk = kt * 32;
        const short* Ap = (const short*)A0_; const short* Wp = W0;
        if (TWO && kk >= 1024) { Ap = (const short*)A1_; Wp = W1; kk &= 1023; }
#pragma unroll
        for (int i = 0; i < 2; ++i) {
            int rbase = wid * 32 + i * 16;
            const short* ga = Ap + (size_t)(m0 + rbase + arow) * K + kk + lq8;
            const short* gw = Wp + (size_t)(n0 + rbase + arow) * K + kk + lq8;
            __builtin_amdgcn_global_load_lds((glb_u32*)ga,
                (lds_u32*)(As + buf * 4096 + rbase * 32), 16, 0, 0);
            __builtin_amdgcn_global_load_lds((glb_u32*)gw,
                (lds_u32*)(Ws + buf * 4096 + rbase * 32), 16, 0, 0);
        }
    };

    // ---- AF32 path staging: f32 reg load + cvt_pk + slot-swizzled LDS write
    const int srow = tid >> 1, shalf = tid & 1;
    f32x4 a0g, a1g, a2g, a3g;
    s16x8 wg0, wg1;
    auto load_regs = [&](int kt) {
        int kk = kt * 32;
        const float* Ap = (const float*)A0_; const short* Wp = W0;
        if (TWO && kk >= 1024) { Ap = (const float*)A1_; Wp = W1; kk &= 1023; }
        const short* wp = Wp + (size_t)(n0 + srow) * K + kk + shalf * 16;
        wg0 = *(const s16x8*)wp;
        wg1 = *(const s16x8*)(wp + 8);
        const float* ap = Ap + (size_t)(m0 + srow) * K + kk + shalf * 16;
        a0g = *(const f32x4*)ap;       a1g = *(const f32x4*)(ap + 4);
        a2g = *(const f32x4*)(ap + 8); a3g = *(const f32x4*)(ap + 12);
    };
    auto store_lds = [&](int buf) {
        s16x8 s0 = pack8(a0g, a1g);       // K-quarter 2*shalf
        s16x8 s1 = pack8(a2g, a3g);       // K-quarter 2*shalf+1
        int sw = (srow >> 1) & 3;
        int ph0 = (shalf * 2) ^ sw, ph1 = (shalf * 2 + 1) ^ sw;
        char* ab = (char*)(As + buf * 4096);
        *(s16x8*)(ab + srow * 64 + ph0 * 16) = s0;
        *(s16x8*)(ab + srow * 64 + ph1 * 16) = s1;
        char* wb = (char*)(Ws + buf * 4096);
        *(s16x8*)(wb + srow * 64 + ph0 * 16) = wg0;
        *(s16x8*)(wb + srow * 64 + ph1 * 16) = wg1;
    };

    f32x4 z = {0.f, 0.f, 0.f, 0.f};
    f32x4 acc[4][4];
#pragma unroll
    for (int i = 0; i < 4; ++i)
#pragma unroll
        for (int j = 0; j < 4; ++j) acc[i][j] = z;

    // shared swizzled read offsets: row = base16 + r -> (row>>1)&3 == (r>>1)&3
    const int sl = (g ^ ((r >> 1) & 3)) << 3;
    auto compute = [&](int buf) {
        s16x8 af[4], bfr[4];
#pragma unroll
        for (int f = 0; f < 4; ++f) {
            af[f]  = *(const s16x8*)(As + buf * 4096 + (wm * 64 + f * 16 + r) * 32 + sl);
            bfr[f] = *(const s16x8*)(Ws + buf * 4096 + (wn * 64 + f * 16 + r) * 32 + sl);
        }
#pragma unroll
        for (int i = 0; i < 4; ++i)
#pragma unroll
            for (int j = 0; j < 4; ++j)
                acc[i][j] = __builtin_amdgcn_mfma_f32_16x16x32_bf16(af[i], bfr[j], acc[i][j], 0, 0, 0);
    };

    constexpr int NK = TWO ? 64 : 32;
    if constexpr (AF32) {
        load_regs(0); store_lds(0);
        __syncthreads();
        int buf = 0;
        for (int kt = 0; kt < NK; ++kt) {
            if (kt + 1 < NK) load_regs(kt + 1);
            compute(buf);
            if (kt + 1 < NK) store_lds(buf ^ 1);
            __syncthreads();
            buf ^= 1;
        }
    } else {
        stage(0, 0);
        stage(1, 1);
        for (int t = 0; t < NK; ++t) {
            if (t + 1 < NK) asm volatile("s_waitcnt vmcnt(4)" ::: "memory");
            else            asm volatile("s_waitcnt vmcnt(0)" ::: "memory");
            __builtin_amdgcn_s_barrier();
            if (t + 2 < NK) stage((t + 2) % 3, t + 2);
            compute(t % 3);
        }
    }

    // epilogue: C layout col=lane&15, row=(lane>>4)*4+reg
#pragma unroll
    for (int j = 0; j < 4; ++j) {
        int col = n0 + wn * 64 + j * 16 + r;
        float bb = b0[col];
        if (TWO) bb += b1[col];
#pragma unroll
        for (int i = 0; i < 4; ++i) {
            int rowb = m0 + wm * 64 + i * 16 + g * 4;
            if constexpr (OUTMODE == 2) {
                // V^T per head, pi-permuted pos (rowb%4==0 so tok[1:0]=0)
                int bb_ = rowb >> 10, tok = rowb & 1023;
                int tokp = (tok & ~31) | (((tok >> 2) & 3) << 3) | (((tok >> 4) & 1) << 2);
                short* dst = (short*)C_ + ((size_t)(bb_ * 16 + (col >> 6))) * 65536
                           + (size_t)(col & 63) * 1024 + tokp;
                s16x4 o;
#pragma unroll
                for (int q = 0; q < 4; ++q) o[q] = f2b(acc[i][j][q] + bb);
                *(s16x4*)dst = o;
            } else {
#pragma unroll
                for (int q = 0; q < 4; ++q) {
                    float val = acc[i][j][q] + bb;
                    if constexpr (OUTMODE == 1)
                        ((float*)C_)[(size_t)(rowb + q) * N + col] = val;
                    else if constexpr (OUTMODE == 3)
                        ((short*)C_)[(size_t)(rowb + q) * N + col] = f2b(val * QSCL);
                    else
                        ((short*)C_)[(size_t)(rowb + q) * N + col] = f2b(val);
                }
            }
        }
    }
}

// ---------------- qr projection: AF32, raw f32 q,r (round-8 measured) --------
__global__ __launch_bounds__(256) void proj_qr(
    const float* __restrict__ qf, const float* __restrict__ rf,
    const short* __restrict__ Wq, const short* __restrict__ Wr,
    const float* __restrict__ bq, const float* __restrict__ br,
    short* __restrict__ qrb)
{
    __shared__ alignas(16) short As[2 * 4096];   // AF32 path: 2 buffers, 32 KB
    __shared__ alignas(16) short Ws[2 * 4096];
    const int bid = blockIdx.x;
    const int logical = (bid & 7) * 64 + (bid >> 3);   // XCD-chunked, 512%8==0
    gemm_body<1, 3, 1>(logical, qf, rf, Wq, Wr, bq, br, qrb, As, Ws);
}

// ---------------- v & k projections: T4-lite bf16 (round-12 measured) --------
__global__ __launch_bounds__(256) void proj_vk(
    const short* __restrict__ vb, const short* __restrict__ kb,
    const short* __restrict__ Wb,
    const float* __restrict__ bv, const float* __restrict__ bk,
    short* __restrict__ vtb, short* __restrict__ khb)
{
    __shared__ alignas(16) short As[3 * 4096];
    __shared__ alignas(16) short Ws[3 * 4096];
    const int bid = blockIdx.x;
    const int lb = bid & 511;
    const int logical = (lb & 7) * 64 + (lb >> 3);
    if (bid < 512)
        gemm_body<0, 2, 0>(logical, vb, nullptr, Wb, nullptr, bv, nullptr, vtb, As, Ws);
    else
        gemm_body<0, 0, 0>(logical, kb, nullptr, Wb + 1048576u, nullptr, bk, nullptr, khb, As, Ws);
}

// ---------------- output projection (bf16 A, T4-lite) ------------------------
__global__ __launch_bounds__(256) void gemm_out(
    const short* __restrict__ att, const short* __restrict__ Wm,
    const float* __restrict__ bm, float* __restrict__ out)
{
    __shared__ alignas(16) short As[3 * 4096];
    __shared__ alignas(16) short Ws[3 * 4096];
    const int bid = blockIdx.x;
    const int logical = (bid & 7) * 64 + (bid >> 3);
    gemm_body<0, 1, 0>(logical, att, nullptr, Wm, nullptr, bm, nullptr, out, As, Ws);
}

// ---------------- flash attention (round-8 verified, unchanged) --------------
__global__ __launch_bounds__(256) void attn_fwd(
    const short* __restrict__ qrh, const short* __restrict__ kh,
    const short* __restrict__ vT, const int* __restrict__ mask,
    short* __restrict__ outp)
{
    const int bh = blockIdx.x;
    const int b = bh >> 4, h = bh & 15;
    const int qt = blockIdx.y;
    const int tid = threadIdx.x, lane = tid & 63, wid = tid >> 6;
    const int r = lane & 15, g = lane >> 4;

    __shared__ alignas(16) short Ks[64 * 64];   // [tok][d], 16B slot ^= row&7
    __shared__ alignas(16) short Vs[64 * 64];   // [d][pos], same swizzle
    __shared__ alignas(16) float mb[1024];      // premask (exp2 domain), whole row

    {   // premask: mask[b][tok] ? MASKV : 0
        i32x4 mi = *(const i32x4*)(mask + b * 1024 + tid * 4);
        f32x4 mv;
#pragma unroll
        for (int j = 0; j < 4; ++j) mv[j] = mi[j] ? MASKV : 0.f;
        *(f32x4*)&mb[tid * 4] = mv;
    }

    const int q0 = qt * 128 + wid * 32;
    const short* qbA = qrh + (size_t)(b * 1024 + q0 + r) * 1024 + h * 64;
    const short* qbB = qbA + 16 * 1024;
    s16x8 qA0 = *(const s16x8*)(qbA + g * 8);
    s16x8 qA1 = *(const s16x8*)(qbA + 32 + g * 8);
    s16x8 qB0 = *(const s16x8*)(qbB + g * 8);
    s16x8 qB1 = *(const s16x8*)(qbB + 32 + g * 8);

    f32x4 z = {0.f, 0.f, 0.f, 0.f};
    f32x4 oA[4], oB[4];
#pragma unroll
    for (int i = 0; i < 4; ++i) { oA[i] = z; oB[i] = z; }
    float lA = 0.f, lB = 0.f;

    // staging: thread (srow, sq) covers row srow, 16 elems at sq*16
    const int srow = tid >> 2, sq = tid & 3;
    const short* kg = kh + (size_t)(b * 1024 + srow) * 1024 + h * 64 + sq * 16;
    const short* vg = vT + ((size_t)(b * 16 + h)) * 65536 + (size_t)srow * 1024 + sq * 16;
    const int p0s = (sq * 2) ^ (srow & 7), p1s = (sq * 2 + 1) ^ (srow & 7);

    s16x8 kr0, kr1, vr0, vr1;
    auto stage_load = [&](int t) {
        const short* kp = kg + (size_t)(t * 64) * 1024;
        kr0 = *(const s16x8*)kp; kr1 = *(const s16x8*)(kp + 8);
        const short* vp = vg + t * 64;
        vr0 = *(const s16x8*)vp; vr1 = *(const s16x8*)(vp + 8);
    };
    auto stage_write = [&]() {
        char* kb2 = (char*)Ks;
        *(s16x8*)(kb2 + srow * 128 + p0s * 16) = kr0;
        *(s16x8*)(kb2 + srow * 128 + p1s * 16) = kr1;
        char* vb2 = (char*)Vs;
        *(s16x8*)(vb2 + srow * 128 + p0s * 16) = vr0;
        *(s16x8*)(vb2 + srow * 128 + p1s * 16) = vr1;
    };

    stage_load(0);
    for (int t = 0; t < 16; ++t) {
        if (t) __syncthreads();
        stage_write();
        __syncthreads();
        if (t < 15) stage_load(t + 1);   // issue next tile loads early

        // QK^T swapped; scores pre-scaled (exp2 domain); P = exp2(score + mask)
        f32x4 pA[4], pB[4];
        char* kb2 = (char*)Ks;
        float tsA = 0.f, tsB = 0.f;
#pragma unroll
        for (int fn = 0; fn < 4; ++fn) {
            int row = fn * 16 + r;
            s16x8 kfa = *(const s16x8*)(kb2 + row * 128 + ((g ^ (row & 7)) << 4));
            s16x8 kfb = *(const s16x8*)(kb2 + row * 128 + (((4 + g) ^ (row & 7)) << 4));
            f32x4 cA = __builtin_amdgcn_mfma_f32_16x16x32_bf16(kfa, qA0, z, 0, 0, 0);
            cA = __builtin_amdgcn_mfma_f32_16x16x32_bf16(kfb, qA1, cA, 0, 0, 0);
            f32x4 cB = __builtin_amdgcn_mfma_f32_16x16x32_bf16(kfa, qB0, z, 0, 0, 0);
            cB = __builtin_amdgcn_mfma_f32_16x16x32_bf16(kfb, qB1, cB, 0, 0, 0);
            f32x4 mv = *(const f32x4*)&mb[t * 64 + fn * 16 + g * 4];
#pragma unroll
            for (int qi = 0; qi < 4; ++qi) {
                float eA = vexp2(cA[qi] + mv[qi]); pA[fn][qi] = eA; tsA += eA;
                float eB = vexp2(cB[qi] + mv[qi]); pB[fn][qi] = eB; tsB += eB;
            }
        }
        tsA += __shfl_xor(tsA, 16); tsA += __shfl_xor(tsA, 32);
        tsB += __shfl_xor(tsB, 16); tsB += __shfl_xor(tsB, 32);
        lA += tsA; lB += tsB;

        // PV: pi-permuted V -> one b128 A-frag per (ks,df)
        char* vb2 = (char*)Vs;
#pragma unroll
        for (int ks = 0; ks < 2; ++ks) {
            s16x8 pbA = pack8(pA[2 * ks], pA[2 * ks + 1]);
            s16x8 pbB = pack8(pB[2 * ks], pB[2 * ks + 1]);
#pragma unroll
            for (int df = 0; df < 4; ++df) {
                int row = df * 16 + r;
                int slot = (ks * 4 + g) ^ (row & 7);
                s16x8 vf = *(const s16x8*)(vb2 + row * 128 + (slot << 4));
                oA[df] = __builtin_amdgcn_mfma_f32_16x16x32_bf16(vf, pbA, oA[df], 0, 0, 0);
                oB[df] = __builtin_amdgcn_mfma_f32_16x16x32_bf16(vf, pbB, oB[df], 0, 0, 0);
            }
        }
    }

    // epilogue
    float ivA = 1.f / lA, ivB = 1.f / lB;
#pragma unroll
    for (int df = 0; df < 4; ++df) {
        s16x4 oa, ob;
#pragma unroll
        for (int qi = 0; qi < 4; ++qi) {
            oa[qi] = f2b(oA[df][qi] * ivA);
            ob[qi] = f2b(oB[df][qi] * ivB);
        }
        *(s16x4*)&outp[(size_t)(b * 1024 + q0 + r) * 1024 + h * 64 + df * 16 + g * 4] = oa;
        *(s16x4*)&outp[(size_t)(b * 1024 + q0 + 16 + r) * 1024 + h * 64 + df * 16 + g * 4] = ob;
    }
}

// ---------------- launch ----------------
extern "C" void kernel_launch(void* const* d_in, const int* in_sizes, int n_in,
                              void* d_out, int out_size, void* d_ws, size_t ws_size,
                              hipStream_t stream) {
    const float* v  = (const float*)d_in[0];
    const float* k  = (const float*)d_in[1];
    const float* q  = (const float*)d_in[2];
    const float* rr = (const float*)d_in[3];
    const int* mask = (const int*)d_in[4];
    const float* Wv = (const float*)d_in[5];  const float* bv = (const float*)d_in[6];
    const float* Wk = (const float*)d_in[7];  const float* bk = (const float*)d_in[8];
    const float* Wq = (const float*)d_in[9];  const float* bq = (const float*)d_in[10];
    const float* Wr = (const float*)d_in[11]; const float* br = (const float*)d_in[12];
    const float* Wm = (const float*)d_in[13]; const float* bm = (const float*)d_in[14];

    const size_t MB = 1048576u;
    const size_t NEED = 90u * MB;   // W 10 + vb 16 + kb 16 + vtb 16 + khb 16 + qrb 16
    if (ws_size < NEED) return;     // leaves poison -> visible failure

    // Buffer lifetimes: vb,kb consumed by proj_vk; att overwrites vb after.
    char* ws = (char*)d_ws;
    short* Wb  = (short*)ws;                  // 5 x 1M bf16
    short* vb  = (short*)(ws + 10u * MB);     // v bf16 (A for v-proj; later att)
    short* kb  = (short*)(ws + 26u * MB);     // k bf16
    short* vtb = (short*)(ws + 42u * MB);     // V^T [b][h][d][pos]
    short* khb = (short*)(ws + 58u * MB);     // K heads row-major
    short* qrb = (short*)(ws + 74u * MB);     // (q+r) heads, pre-scaled QSCL
    short* att = vb;                          // vb dead after proj_vk

    Ptr7 t7;
    t7.p[0] = v;  t7.p[1] = k;
    t7.p[2] = Wv; t7.p[3] = Wk; t7.p[4] = Wq; t7.p[5] = Wr; t7.p[6] = Wm;
    cvt_all<<<dim3(10752), 256, 0, stream>>>(t7, vb, kb, Wb);

    proj_qr<<<dim3(512), 256, 0, stream>>>(q, rr, Wb + 2097152u, Wb + 3145728u,
                                           bq, br, qrb);
    proj_vk<<<dim3(1024), 256, 0, stream>>>(vb, kb, Wb, bv, bk, vtb, khb);

    attn_fwd<<<dim3(128, 8), 256, 0, stream>>>(qrb, khb, vtb, mask, att);

    gemm_out<<<dim3(512), 256, 0, stream>>>(att, Wb + 4194304u, bm, (float*)d_out);
}

// Round 16
// 232.268 us; speedup vs baseline: 1.0276x; 1.0276x over previous
//
#include <hip/hip_runtime.h>
#include <hip/hip_bf16.h>
#include <stdint.h>

typedef __attribute__((ext_vector_type(4))) float f32x4;
typedef __attribute__((ext_vector_type(8))) short s16x8;
typedef __attribute__((ext_vector_type(4))) short s16x4;
typedef __attribute__((ext_vector_type(4))) int i32x4;

typedef const __attribute__((address_space(1))) unsigned glb_u32;
typedef __attribute__((address_space(3))) unsigned lds_u32;

#define DEVI __device__ __forceinline__

DEVI short f2b(float f) {
    union { float f; unsigned u; } v; v.f = f;
    unsigned r = v.u + 0x7fffu + ((v.u >> 16) & 1u);
    return (short)(r >> 16);
}

DEVI float vexp2(float x) {           // raw v_exp_f32: 2^x
    float r;
    asm("v_exp_f32 %0, %1" : "=v"(r) : "v"(x));
    return r;
}

DEVI unsigned cvtpk(float lo, float hi) {   // d.bf16[0]=lo, d.bf16[1]=hi (RNE)
    unsigned d;
    asm("v_cvt_pk_bf16_f32 %0, %1, %2" : "=v"(d) : "v"(lo), "v"(hi));
    return d;
}

DEVI s16x8 pack8(const f32x4& a, const f32x4& b) {  // v[0..3]=a, v[4..7]=b
    union { unsigned u[4]; s16x8 v; } w;
    w.u[0] = cvtpk(a[0], a[1]);
    w.u[1] = cvtpk(a[2], a[3]);
    w.u[2] = cvtpk(b[0], b[1]);
    w.u[3] = cvtpk(b[2], b[3]);
    return w.v;
}

// exp2-domain constants. qr is pre-scaled by QSCL in its GEMM epilogue, so
// QK^T MFMA output is already score*log2(e); softmax needs NO max-shift.
#define QSCL 0.18033688011112042f      /* 0.125 * log2(e) */
#define MASKV -1.4426950408889634e9f   /* -1e9 * log2(e); exp2 -> exact 0 */

// ---------------- fused convert: v, k (8M elems each) + 5 weights -> bf16 ----
struct Ptr7 { const float* p[7]; };   // v, k, Wv, Wk, Wq, Wr, Wm

__global__ __launch_bounds__(256) void cvt_all(Ptr7 t, short* __restrict__ vb,
                                               short* __restrict__ kb,
                                               short* __restrict__ Wb) {
    int bid = blockIdx.x;             // 0..10751
    const float* s; short* d; int off;
    if (bid < 4096)      { s = t.p[0]; d = vb; off = bid; }
    else if (bid < 8192) { s = t.p[1]; d = kb; off = bid - 4096; }
    else {
        int w = (bid - 8192) >> 9;
        s = t.p[2 + w]; d = Wb + (size_t)w * 1048576u; off = (bid - 8192) & 511;
    }
    int i = (off * 256 + threadIdx.x) * 8;
    f32x4 a = *(const f32x4*)(s + i);
    f32x4 b = *(const f32x4*)(s + i + 4);
    *(s16x8*)(d + i) = pack8(a, b);
}

// ---------------- NT GEMM body (round-9 verified) ----------------------------
// AF32: A is f32 (reg-staged with cvt_pk convert); else bf16 via global_load_lds.
// OUTMODE: 0 bf16 row-major | 1 f32 row-major | 2 bf16 per-head-transposed
//          [b][h][d][pos], pos = pi(tok): pos[4:3]=tok[3:2], pos[2]=tok[4],
//          pos[1:0]=tok[1:0] (attn V) | 3 bf16 row-major scaled QSCL (attn qr).
// TWO: C = A0*W0^T + A1*W1^T + b0 + b1 (K=2*1024).
template<int AF32, int OUTMODE, int TWO>
DEVI void gemm_body(int logical,
                    const void* A0_, const void* A1_,
                    const short* W0, const short* W1,
                    const float* b0, const float* b1,
                    void* C_, short* As, short* Ws)
{
    constexpr int K = 1024, N = 1024;
    const int tid = threadIdx.x;
    const int lane = tid & 63, wid = tid >> 6;
    const int wm = wid >> 1, wn = wid & 1;
    const int r = lane & 15, g = lane >> 4;
    const int n0 = (logical & 7) * 128, m0 = (logical >> 3) * 128;

    auto stage_async = [&](int buf, int kt) {   // bf16 A path
        int kk = kt * 32;
        const short* Ap = (const short*)A0_; const short* Wp = W0;
        if (TWO && kk >= 1024) { Ap = (const short*)A1_; Wp = W1; kk &= 1023; }
#pragma unroll
        for (int i = 0; i < 2; ++i) {
            int row = wid * 32 + i * 16 + (lane >> 2);
            const short* ga = Ap + (size_t)(m0 + row) * K + kk + (lane & 3) * 8;
            const short* gw = Wp + (size_t)(n0 + row) * K + kk + (lane & 3) * 8;
            __builtin_amdgcn_global_load_lds((glb_u32*)ga,
                (lds_u32*)(As + buf * 4096 + (wid * 32 + i * 16) * 32), 16, 0, 0);
            __builtin_amdgcn_global_load_lds((glb_u32*)gw,
                (lds_u32*)(Ws + buf * 4096 + (wid * 32 + i * 16) * 32), 16, 0, 0);
        }
    };

    const int srow = tid >> 1, shalf = tid & 1;   // f32 A path staging
    f32x4 a0g, a1g, a2g, a3g;
    s16x8 wg0, wg1;
    auto load_regs = [&](int kt) {
        int kk = kt * 32;
        const float* Ap = (const float*)A0_; const short* Wp = W0;
        if (TWO && kk >= 1024) { Ap = (const float*)A1_; Wp = W1; kk &= 1023; }
        const short* wp = Wp + (size_t)(n0 + srow) * K + kk + shalf * 16;
        wg0 = *(const s16x8*)wp;
        wg1 = *(const s16x8*)(wp + 8);
        const float* ap = Ap + (size_t)(m0 + srow) * K + kk + shalf * 16;
        a0g = *(const f32x4*)ap;       a1g = *(const f32x4*)(ap + 4);
        a2g = *(const f32x4*)(ap + 8); a3g = *(const f32x4*)(ap + 12);
    };
    auto store_lds = [&](int buf) {
        s16x8 s0 = pack8(a0g, a1g);
        s16x8 s1 = pack8(a2g, a3g);
        char* ab = (char*)(As + buf * 4096);
        *(s16x8*)(ab + srow * 64 + shalf * 32) = s0;
        *(s16x8*)(ab + srow * 64 + shalf * 32 + 16) = s1;
        char* wb = (char*)(Ws + buf * 4096);
        *(s16x8*)(wb + srow * 64 + shalf * 32) = wg0;
        *(s16x8*)(wb + srow * 64 + shalf * 32 + 16) = wg1;
    };

    f32x4 z = {0.f, 0.f, 0.f, 0.f};
    f32x4 acc[4][4];
#pragma unroll
    for (int i = 0; i < 4; ++i)
#pragma unroll
        for (int j = 0; j < 4; ++j) acc[i][j] = z;

    auto compute = [&](int buf) {
        s16x8 af[4], bfr[4];
#pragma unroll
        for (int f = 0; f < 4; ++f) {
            af[f]  = *(const s16x8*)(As + buf * 4096 + (wm * 64 + f * 16 + r) * 32 + g * 8);
            bfr[f] = *(const s16x8*)(Ws + buf * 4096 + (wn * 64 + f * 16 + r) * 32 + g * 8);
        }
#pragma unroll
        for (int i = 0; i < 4; ++i)
#pragma unroll
            for (int j = 0; j < 4; ++j)
                acc[i][j] = __builtin_amdgcn_mfma_f32_16x16x32_bf16(af[i], bfr[j], acc[i][j], 0, 0, 0);
    };

    constexpr int NK = TWO ? 64 : 32;
    if constexpr (AF32) { load_regs(0); store_lds(0); }
    else stage_async(0, 0);
    __syncthreads();
    int buf = 0;
    for (int kt = 0; kt < NK; ++kt) {
        if (kt + 1 < NK) {
            if constexpr (AF32) load_regs(kt + 1);
            else stage_async(buf ^ 1, kt + 1);
        }
        compute(buf);
        if (AF32 && kt + 1 < NK) store_lds(buf ^ 1);
        __syncthreads();
        buf ^= 1;
    }

    // epilogue: C layout col=lane&15, row=(lane>>4)*4+reg
#pragma unroll
    for (int j = 0; j < 4; ++j) {
        int col = n0 + wn * 64 + j * 16 + r;
        float bb = b0[col];
        if (TWO) bb += b1[col];
#pragma unroll
        for (int i = 0; i < 4; ++i) {
            int rowb = m0 + wm * 64 + i * 16 + g * 4;
            if constexpr (OUTMODE == 2) {
                // V^T per head, pi-permuted pos (rowb%4==0 so tok[1:0]=0)
                int bb_ = rowb >> 10, tok = rowb & 1023;
                int tokp = (tok & ~31) | (((tok >> 2) & 3) << 3) | (((tok >> 4) & 1) << 2);
                short* dst = (short*)C_ + ((size_t)(bb_ * 16 + (col >> 6))) * 65536
                           + (size_t)(col & 63) * 1024 + tokp;
                s16x4 o;
#pragma unroll
                for (int q = 0; q < 4; ++q) o[q] = f2b(acc[i][j][q] + bb);
                *(s16x4*)dst = o;
            } else {
#pragma unroll
                for (int q = 0; q < 4; ++q) {
                    float val = acc[i][j][q] + bb;
                    if constexpr (OUTMODE == 1)
                        ((float*)C_)[(size_t)(rowb + q) * N + col] = val;
                    else if constexpr (OUTMODE == 3)
                        ((short*)C_)[(size_t)(rowb + q) * N + col] = f2b(val * QSCL);
                    else
                        ((short*)C_)[(size_t)(rowb + q) * N + col] = f2b(val);
                }
            }
        }
    }
}

// ---------------- merged projections: qr-proj | v-proj | k-proj --------------
// grid 1536, sub = bid>>9 (block-uniform branch). LONGEST-JOB-FIRST: the qr
// blocks (K=2048, 2x duration) take sub==0 so they are dispatched FIRST and
// their extra length overlaps the v/k blocks instead of forming a serial tail
// (round-9 had qr last; this is a pure blockIdx->work relabeling).
// Per-sub XCD-chunked bijective swizzle (512 % 8 == 0).
__global__ __launch_bounds__(256) void proj_all(
    const short* __restrict__ vb, const short* __restrict__ kb,
    const float* __restrict__ qf, const float* __restrict__ rf,
    const short* __restrict__ Wb,
    const float* __restrict__ bv, const float* __restrict__ bk,
    const float* __restrict__ bq, const float* __restrict__ br,
    short* __restrict__ vtb, short* __restrict__ khb, short* __restrict__ qrb)
{
    __shared__ alignas(16) short As[2 * 128 * 32];
    __shared__ alignas(16) short Ws[2 * 128 * 32];
    const int bid = blockIdx.x;
    const int sub = bid >> 9, lbid = bid & 511;
    const int logical = (lbid & 7) * 64 + (lbid >> 3);
    if (sub == 0)
        gemm_body<1, 3, 1>(logical, qf, rf, Wb + 2097152u, Wb + 3145728u, bq, br, qrb, As, Ws);
    else if (sub == 1)
        gemm_body<0, 2, 0>(logical, vb, nullptr, Wb, nullptr, bv, nullptr, vtb, As, Ws);
    else
        gemm_body<0, 0, 0>(logical, kb, nullptr, Wb + 1048576u, nullptr, bk, nullptr, khb, As, Ws);
}

// ---------------- standalone GEMM (output projection) ------------------------
template<int AF32, int OUTMODE, int TWO>
__global__ __launch_bounds__(256) void gemm_nt(
    const void* __restrict__ A0_, const void* __restrict__ A1_,
    const short* __restrict__ W0, const short* __restrict__ W1,
    const float* __restrict__ b0, const float* __restrict__ b1,
    void* __restrict__ C_)
{
    __shared__ alignas(16) short As[2 * 128 * 32];
    __shared__ alignas(16) short Ws[2 * 128 * 32];
    const int bid = blockIdx.x;
    const int logical = (bid & 7) * 64 + (bid >> 3);
    gemm_body<AF32, OUTMODE, TWO>(logical, A0_, A1_, W0, W1, b0, b1, C_, As, Ws);
}

// ---------------- flash attention (round-8 verified, unchanged) --------------
__global__ __launch_bounds__(256) void attn_fwd(
    const short* __restrict__ qrh, const short* __restrict__ kh,
    const short* __restrict__ vT, const int* __restrict__ mask,
    short* __restrict__ outp)
{
    const int bh = blockIdx.x;
    const int b = bh >> 4, h = bh & 15;
    const int qt = blockIdx.y;
    const int tid = threadIdx.x, lane = tid & 63, wid = tid >> 6;
    const int r = lane & 15, g = lane >> 4;

    __shared__ alignas(16) short Ks[64 * 64];   // [tok][d], 16B slot ^= row&7
    __shared__ alignas(16) short Vs[64 * 64];   // [d][pos], same swizzle
    __shared__ alignas(16) float mb[1024];      // premask (exp2 domain), whole row

    {   // premask: mask[b][tok] ? MASKV : 0
        i32x4 mi = *(const i32x4*)(mask + b * 1024 + tid * 4);
        f32x4 mv;
#pragma unroll
        for (int j = 0; j < 4; ++j) mv[j] = mi[j] ? MASKV : 0.f;
        *(f32x4*)&mb[tid * 4] = mv;
    }

    const int q0 = qt * 128 + wid * 32;
    const short* qbA = qrh + (size_t)(b * 1024 + q0 + r) * 1024 + h * 64;
    const short* qbB = qbA + 16 * 1024;
    s16x8 qA0 = *(const s16x8*)(qbA + g * 8);
    s16x8 qA1 = *(const s16x8*)(qbA + 32 + g * 8);
    s16x8 qB0 = *(const s16x8*)(qbB + g * 8);
    s16x8 qB1 = *(const s16x8*)(qbB + 32 + g * 8);

    f32x4 z = {0.f, 0.f, 0.f, 0.f};
    f32x4 oA[4], oB[4];
#pragma unroll
    for (int i = 0; i < 4; ++i) { oA[i] = z; oB[i] = z; }
    float lA = 0.f, lB = 0.f;

    // staging: thread (srow, sq) covers row srow, 16 elems at sq*16
    const int srow = tid >> 2, sq = tid & 3;
    const short* kg = kh + (size_t)(b * 1024 + srow) * 1024 + h * 64 + sq * 16;
    const short* vg = vT + ((size_t)(b * 16 + h)) * 65536 + (size_t)srow * 1024 + sq * 16;
    const int p0s = (sq * 2) ^ (srow & 7), p1s = (sq * 2 + 1) ^ (srow & 7);

    s16x8 kr0, kr1, vr0, vr1;
    auto stage_load = [&](int t) {
        const short* kp = kg + (size_t)(t * 64) * 1024;
        kr0 = *(const s16x8*)kp; kr1 = *(const s16x8*)(kp + 8);
        const short* vp = vg + t * 64;
        vr0 = *(const s16x8*)vp; vr1 = *(const s16x8*)(vp + 8);
    };
    auto stage_write = [&]() {
        char* kb2 = (char*)Ks;
        *(s16x8*)(kb2 + srow * 128 + p0s * 16) = kr0;
        *(s16x8*)(kb2 + srow * 128 + p1s * 16) = kr1;
        char* vb2 = (char*)Vs;
        *(s16x8*)(vb2 + srow * 128 + p0s * 16) = vr0;
        *(s16x8*)(vb2 + srow * 128 + p1s * 16) = vr1;
    };

    stage_load(0);
    for (int t = 0; t < 16; ++t) {
        if (t) __syncthreads();
        stage_write();
        __syncthreads();
        if (t < 15) stage_load(t + 1);   // issue next tile loads early

        // QK^T swapped; scores pre-scaled (exp2 domain); P = exp2(score + mask)
        f32x4 pA[4], pB[4];
        char* kb2 = (char*)Ks;
        float tsA = 0.f, tsB = 0.f;
#pragma unroll
        for (int fn = 0; fn < 4; ++fn) {
            int row = fn * 16 + r;
            s16x8 kfa = *(const s16x8*)(kb2 + row * 128 + ((g ^ (row & 7)) << 4));
            s16x8 kfb = *(const s16x8*)(kb2 + row * 128 + (((4 + g) ^ (row & 7)) << 4));
            f32x4 cA = __builtin_amdgcn_mfma_f32_16x16x32_bf16(kfa, qA0, z, 0, 0, 0);
            cA = __builtin_amdgcn_mfma_f32_16x16x32_bf16(kfb, qA1, cA, 0, 0, 0);
            f32x4 cB = __builtin_amdgcn_mfma_f32_16x16x32_bf16(kfa, qB0, z, 0, 0, 0);
            cB = __builtin_amdgcn_mfma_f32_16x16x32_bf16(kfb, qB1, cB, 0, 0, 0);
            f32x4 mv = *(const f32x4*)&mb[t * 64 + fn * 16 + g * 4];
#pragma unroll
            for (int qi = 0; qi < 4; ++qi) {
                float eA = vexp2(cA[qi] + mv[qi]); pA[fn][qi] = eA; tsA += eA;
                float eB = vexp2(cB[qi] + mv[qi]); pB[fn][qi] = eB; tsB += eB;
            }
        }
        tsA += __shfl_xor(tsA, 16); tsA += __shfl_xor(tsA, 32);
        tsB += __shfl_xor(tsB, 16); tsB += __shfl_xor(tsB, 32);
        lA += tsA; lB += tsB;

        // PV: pi-permuted V -> one b128 A-frag per (ks,df)
        char* vb2 = (char*)Vs;
#pragma unroll
        for (int ks = 0; ks < 2; ++ks) {
            s16x8 pbA = pack8(pA[2 * ks], pA[2 * ks + 1]);
            s16x8 pbB = pack8(pB[2 * ks], pB[2 * ks + 1]);
#pragma unroll
            for (int df = 0; df < 4; ++df) {
                int row = df * 16 + r;
                int slot = (ks * 4 + g) ^ (row & 7);
                s16x8 vf = *(const s16x8*)(vb2 + row * 128 + (slot << 4));
                oA[df] = __builtin_amdgcn_mfma_f32_16x16x32_bf16(vf, pbA, oA[df], 0, 0, 0);
                oB[df] = __builtin_amdgcn_mfma_f32_16x16x32_bf16(vf, pbB, oB[df], 0, 0, 0);
            }
        }
    }

    // epilogue
    float ivA = 1.f / lA, ivB = 1.f / lB;
#pragma unroll
    for (int df = 0; df < 4; ++df) {
        s16x4 oa, ob;
#pragma unroll
        for (int qi = 0; qi < 4; ++qi) {
            oa[qi] = f2b(oA[df][qi] * ivA);
            ob[qi] = f2b(oB[df][qi] * ivB);
        }
        *(s16x4*)&outp[(size_t)(b * 1024 + q0 + r) * 1024 + h * 64 + df * 16 + g * 4] = oa;
        *(s16x4*)&outp[(size_t)(b * 1024 + q0 + 16 + r) * 1024 + h * 64 + df * 16 + g * 4] = ob;
    }
}

// ---------------- launch ----------------
extern "C" void kernel_launch(void* const* d_in, const int* in_sizes, int n_in,
                              void* d_out, int out_size, void* d_ws, size_t ws_size,
                              hipStream_t stream) {
    const float* v  = (const float*)d_in[0];
    const float* k  = (const float*)d_in[1];
    const float* q  = (const float*)d_in[2];
    const float* rr = (const float*)d_in[3];
    const int* mask = (const int*)d_in[4];
    const float* Wv = (const float*)d_in[5];  const float* bv = (const float*)d_in[6];
    const float* Wk = (const float*)d_in[7];  const float* bk = (const float*)d_in[8];
    const float* Wq = (const float*)d_in[9];  const float* bq = (const float*)d_in[10];
    const float* Wr = (const float*)d_in[11]; const float* br = (const float*)d_in[12];
    const float* Wm = (const float*)d_in[13]; const float* bm = (const float*)d_in[14];

    const size_t MB = 1048576u;
    const size_t NEED = 90u * MB;   // W 10 + vb 16 + kb 16 + vtb 16 + khb 16 + qrb 16
    if (ws_size < NEED) return;     // leaves poison -> visible failure

    // Buffer lifetimes: vb,kb consumed by proj_all; att overwrites vb after.
    char* ws = (char*)d_ws;
    short* Wb  = (short*)ws;                  // 5 x 1M bf16
    short* vb  = (short*)(ws + 10u * MB);     // v bf16 (A for v-proj; later att)
    short* kb  = (short*)(ws + 26u * MB);     // k bf16
    short* vtb = (short*)(ws + 42u * MB);     // V^T [b][h][d][pos]
    short* khb = (short*)(ws + 58u * MB);     // K heads row-major
    short* qrb = (short*)(ws + 74u * MB);     // (q+r) heads, pre-scaled QSCL
    short* att = vb;                          // vb dead after proj_all

    Ptr7 t7;
    t7.p[0] = v;  t7.p[1] = k;
    t7.p[2] = Wv; t7.p[3] = Wk; t7.p[4] = Wq; t7.p[5] = Wr; t7.p[6] = Wm;
    cvt_all<<<dim3(10752), 256, 0, stream>>>(t7, vb, kb, Wb);

    proj_all<<<dim3(1536), 256, 0, stream>>>(vb, kb, q, rr, Wb,
                                             bv, bk, bq, br, vtb, khb, qrb);

    attn_fwd<<<dim3(128, 8), 256, 0, stream>>>(qrb, khb, vtb, mask, att);

    gemm_nt<0, 1, 0><<<dim3(512), 256, 0, stream>>>(att, nullptr, Wb + 4194304u,
                                                    nullptr, bm, nullptr, (float*)d_out);
}

// Round 17
// 223.184 us; speedup vs baseline: 1.0694x; 1.0407x over previous
//
#include <hip/hip_runtime.h>
#include <hip/hip_bf16.h>
#include <stdint.h>

typedef __attribute__((ext_vector_type(4))) float f32x4;
typedef __attribute__((ext_vector_type(8))) short s16x8;
typedef __attribute__((ext_vector_type(4))) short s16x4;
typedef __attribute__((ext_vector_type(4))) int i32x4;

typedef const __attribute__((address_space(1))) unsigned glb_u32;
typedef __attribute__((address_space(3))) unsigned lds_u32;

#define DEVI __device__ __forceinline__

DEVI short f2b(float f) {
    union { float f; unsigned u; } v; v.f = f;
    unsigned r = v.u + 0x7fffu + ((v.u >> 16) & 1u);
    return (short)(r >> 16);
}

DEVI float vexp2(float x) {           // raw v_exp_f32: 2^x
    float r;
    asm("v_exp_f32 %0, %1" : "=v"(r) : "v"(x));
    return r;
}

DEVI unsigned cvtpk(float lo, float hi) {   // d.bf16[0]=lo, d.bf16[1]=hi (RNE)
    unsigned d;
    asm("v_cvt_pk_bf16_f32 %0, %1, %2" : "=v"(d) : "v"(lo), "v"(hi));
    return d;
}

DEVI s16x8 pack8(const f32x4& a, const f32x4& b) {  // v[0..3]=a, v[4..7]=b
    union { unsigned u[4]; s16x8 v; } w;
    w.u[0] = cvtpk(a[0], a[1]);
    w.u[1] = cvtpk(a[2], a[3]);
    w.u[2] = cvtpk(b[0], b[1]);
    w.u[3] = cvtpk(b[2], b[3]);
    return w.v;
}

// exp2-domain constants. qr is pre-scaled by QSCL in its GEMM epilogue, so
// QK^T MFMA output is already score*log2(e); softmax needs NO max-shift.
#define QSCL 0.18033688011112042f      /* 0.125 * log2(e) */
#define MASKV -1.4426950408889634e9f   /* -1e9 * log2(e); exp2 -> exact 0 */

// ---------------- fused convert: v, k (8M elems each) + 5 weights -> bf16 ----
struct Ptr7 { const float* p[7]; };   // v, k, Wv, Wk, Wq, Wr, Wm

__global__ __launch_bounds__(256) void cvt_all(Ptr7 t, short* __restrict__ vb,
                                               short* __restrict__ kb,
                                               short* __restrict__ Wb) {
    int bid = blockIdx.x;             // 0..10751
    const float* s; short* d; int off;
    if (bid < 4096)      { s = t.p[0]; d = vb; off = bid; }
    else if (bid < 8192) { s = t.p[1]; d = kb; off = bid - 4096; }
    else {
        int w = (bid - 8192) >> 9;
        s = t.p[2 + w]; d = Wb + (size_t)w * 1048576u; off = (bid - 8192) & 511;
    }
    int i = (off * 256 + threadIdx.x) * 8;
    f32x4 a = *(const f32x4*)(s + i);
    f32x4 b = *(const f32x4*)(s + i + 4);
    *(s16x8*)(d + i) = pack8(a, b);
}

// ---------------- NT GEMM body (round-9 verified) ----------------------------
// AF32: A is f32 (reg-staged with cvt_pk convert); else bf16 via global_load_lds.
// OUTMODE: 0 bf16 row-major | 1 f32 row-major | 2 bf16 per-head-transposed
//          [b][h][d][pos], pos = pi(tok): pos[4:3]=tok[3:2], pos[2]=tok[4],
//          pos[1:0]=tok[1:0] (attn V) | 3 bf16 row-major scaled QSCL (attn qr).
// TWO: C = A0*W0^T + A1*W1^T + b0 + b1 (K=2*1024).
template<int AF32, int OUTMODE, int TWO>
DEVI void gemm_body(int logical,
                    const void* A0_, const void* A1_,
                    const short* W0, const short* W1,
                    const float* b0, const float* b1,
                    void* C_, short* As, short* Ws)
{
    constexpr int K = 1024, N = 1024;
    const int tid = threadIdx.x;
    const int lane = tid & 63, wid = tid >> 6;
    const int wm = wid >> 1, wn = wid & 1;
    const int r = lane & 15, g = lane >> 4;
    const int n0 = (logical & 7) * 128, m0 = (logical >> 3) * 128;

    auto stage_async = [&](int buf, int kt) {   // bf16 A path
        int kk = kt * 32;
        const short* Ap = (const short*)A0_; const short* Wp = W0;
        if (TWO && kk >= 1024) { Ap = (const short*)A1_; Wp = W1; kk &= 1023; }
#pragma unroll
        for (int i = 0; i < 2; ++i) {
            int row = wid * 32 + i * 16 + (lane >> 2);
            const short* ga = Ap + (size_t)(m0 + row) * K + kk + (lane & 3) * 8;
            const short* gw = Wp + (size_t)(n0 + row) * K + kk + (lane & 3) * 8;
            __builtin_amdgcn_global_load_lds((glb_u32*)ga,
                (lds_u32*)(As + buf * 4096 + (wid * 32 + i * 16) * 32), 16, 0, 0);
            __builtin_amdgcn_global_load_lds((glb_u32*)gw,
                (lds_u32*)(Ws + buf * 4096 + (wid * 32 + i * 16) * 32), 16, 0, 0);
        }
    };

    const int srow = tid >> 1, shalf = tid & 1;   // f32 A path staging
    f32x4 a0g, a1g, a2g, a3g;
    s16x8 wg0, wg1;
    auto load_regs = [&](int kt) {
        int kk = kt * 32;
        const float* Ap = (const float*)A0_; const short* Wp = W0;
        if (TWO && kk >= 1024) { Ap = (const float*)A1_; Wp = W1; kk &= 1023; }
        const short* wp = Wp + (size_t)(n0 + srow) * K + kk + shalf * 16;
        wg0 = *(const s16x8*)wp;
        wg1 = *(const s16x8*)(wp + 8);
        const float* ap = Ap + (size_t)(m0 + srow) * K + kk + shalf * 16;
        a0g = *(const f32x4*)ap;       a1g = *(const f32x4*)(ap + 4);
        a2g = *(const f32x4*)(ap + 8); a3g = *(const f32x4*)(ap + 12);
    };
    auto store_lds = [&](int buf) {
        s16x8 s0 = pack8(a0g, a1g);
        s16x8 s1 = pack8(a2g, a3g);
        char* ab = (char*)(As + buf * 4096);
        *(s16x8*)(ab + srow * 64 + shalf * 32) = s0;
        *(s16x8*)(ab + srow * 64 + shalf * 32 + 16) = s1;
        char* wb = (char*)(Ws + buf * 4096);
        *(s16x8*)(wb + srow * 64 + shalf * 32) = wg0;
        *(s16x8*)(wb + srow * 64 + shalf * 32 + 16) = wg1;
    };

    f32x4 z = {0.f, 0.f, 0.f, 0.f};
    f32x4 acc[4][4];
#pragma unroll
    for (int i = 0; i < 4; ++i)
#pragma unroll
        for (int j = 0; j < 4; ++j) acc[i][j] = z;

    auto compute = [&](int buf) {
        s16x8 af[4], bfr[4];
#pragma unroll
        for (int f = 0; f < 4; ++f) {
            af[f]  = *(const s16x8*)(As + buf * 4096 + (wm * 64 + f * 16 + r) * 32 + g * 8);
            bfr[f] = *(const s16x8*)(Ws + buf * 4096 + (wn * 64 + f * 16 + r) * 32 + g * 8);
        }
#pragma unroll
        for (int i = 0; i < 4; ++i)
#pragma unroll
            for (int j = 0; j < 4; ++j)
                acc[i][j] = __builtin_amdgcn_mfma_f32_16x16x32_bf16(af[i], bfr[j], acc[i][j], 0, 0, 0);
    };

    constexpr int NK = TWO ? 64 : 32;
    if constexpr (AF32) { load_regs(0); store_lds(0); }
    else stage_async(0, 0);
    __syncthreads();
    int buf = 0;
    for (int kt = 0; kt < NK; ++kt) {
        if (kt + 1 < NK) {
            if constexpr (AF32) load_regs(kt + 1);
            else stage_async(buf ^ 1, kt + 1);
        }
        compute(buf);
        if (AF32 && kt + 1 < NK) store_lds(buf ^ 1);
        __syncthreads();
        buf ^= 1;
    }

    // epilogue: C layout col=lane&15, row=(lane>>4)*4+reg
#pragma unroll
    for (int j = 0; j < 4; ++j) {
        int col = n0 + wn * 64 + j * 16 + r;
        float bb = b0[col];
        if (TWO) bb += b1[col];
#pragma unroll
        for (int i = 0; i < 4; ++i) {
            int rowb = m0 + wm * 64 + i * 16 + g * 4;
            if constexpr (OUTMODE == 2) {
                // V^T per head, pi-permuted pos (rowb%4==0 so tok[1:0]=0)
                int bb_ = rowb >> 10, tok = rowb & 1023;
                int tokp = (tok & ~31) | (((tok >> 2) & 3) << 3) | (((tok >> 4) & 1) << 2);
                short* dst = (short*)C_ + ((size_t)(bb_ * 16 + (col >> 6))) * 65536
                           + (size_t)(col & 63) * 1024 + tokp;
                s16x4 o;
#pragma unroll
                for (int q = 0; q < 4; ++q) o[q] = f2b(acc[i][j][q] + bb);
                *(s16x4*)dst = o;
            } else {
#pragma unroll
                for (int q = 0; q < 4; ++q) {
                    float val = acc[i][j][q] + bb;
                    if constexpr (OUTMODE == 1)
                        ((float*)C_)[(size_t)(rowb + q) * N + col] = val;
                    else if constexpr (OUTMODE == 3)
                        ((short*)C_)[(size_t)(rowb + q) * N + col] = f2b(val * QSCL);
                    else
                        ((short*)C_)[(size_t)(rowb + q) * N + col] = f2b(val);
                }
            }
        }
    }
}

// ---------------- merged projections: v-proj | k-proj | qr-proj --------------
// grid 1536: sub = bid>>9 (block-uniform branch), lbid = bid&511 with the
// XCD-chunked bijective swizzle per sub (512 % 8 == 0). Round-9 ordering.
__global__ __launch_bounds__(256) void proj_all(
    const short* __restrict__ vb, const short* __restrict__ kb,
    const float* __restrict__ qf, const float* __restrict__ rf,
    const short* __restrict__ Wb,
    const float* __restrict__ bv, const float* __restrict__ bk,
    const float* __restrict__ bq, const float* __restrict__ br,
    short* __restrict__ vtb, short* __restrict__ khb, short* __restrict__ qrb)
{
    __shared__ alignas(16) short As[2 * 128 * 32];
    __shared__ alignas(16) short Ws[2 * 128 * 32];
    const int bid = blockIdx.x;
    const int sub = bid >> 9, lbid = bid & 511;
    const int logical = (lbid & 7) * 64 + (lbid >> 3);
    if (sub == 0)
        gemm_body<0, 2, 0>(logical, vb, nullptr, Wb, nullptr, bv, nullptr, vtb, As, Ws);
    else if (sub == 1)
        gemm_body<0, 0, 0>(logical, kb, nullptr, Wb + 1048576u, nullptr, bk, nullptr, khb, As, Ws);
    else
        gemm_body<1, 3, 1>(logical, qf, rf, Wb + 2097152u, Wb + 3145728u, bq, br, qrb, As, Ws);
}

// ---------------- standalone GEMM (output projection) ------------------------
template<int AF32, int OUTMODE, int TWO>
__global__ __launch_bounds__(256) void gemm_nt(
    const void* __restrict__ A0_, const void* __restrict__ A1_,
    const short* __restrict__ W0, const short* __restrict__ W1,
    const float* __restrict__ b0, const float* __restrict__ b1,
    void* __restrict__ C_)
{
    __shared__ alignas(16) short As[2 * 128 * 32];
    __shared__ alignas(16) short Ws[2 * 128 * 32];
    const int bid = blockIdx.x;
    const int logical = (bid & 7) * 64 + (bid >> 3);
    gemm_body<AF32, OUTMODE, TWO>(logical, A0_, A1_, W0, W1, b0, b1, C_, As, Ws);
}

// ---------------- flash attention (round-8 verified, unchanged) --------------
__global__ __launch_bounds__(256) void attn_fwd(
    const short* __restrict__ qrh, const short* __restrict__ kh,
    const short* __restrict__ vT, const int* __restrict__ mask,
    short* __restrict__ outp)
{
    const int bh = blockIdx.x;
    const int b = bh >> 4, h = bh & 15;
    const int qt = blockIdx.y;
    const int tid = threadIdx.x, lane = tid & 63, wid = tid >> 6;
    const int r = lane & 15, g = lane >> 4;

    __shared__ alignas(16) short Ks[64 * 64];   // [tok][d], 16B slot ^= row&7
    __shared__ alignas(16) short Vs[64 * 64];   // [d][pos], same swizzle
    __shared__ alignas(16) float mb[1024];      // premask (exp2 domain), whole row

    {   // premask: mask[b][tok] ? MASKV : 0
        i32x4 mi = *(const i32x4*)(mask + b * 1024 + tid * 4);
        f32x4 mv;
#pragma unroll
        for (int j = 0; j < 4; ++j) mv[j] = mi[j] ? MASKV : 0.f;
        *(f32x4*)&mb[tid * 4] = mv;
    }

    const int q0 = qt * 128 + wid * 32;
    const short* qbA = qrh + (size_t)(b * 1024 + q0 + r) * 1024 + h * 64;
    const short* qbB = qbA + 16 * 1024;
    s16x8 qA0 = *(const s16x8*)(qbA + g * 8);
    s16x8 qA1 = *(const s16x8*)(qbA + 32 + g * 8);
    s16x8 qB0 = *(const s16x8*)(qbB + g * 8);
    s16x8 qB1 = *(const s16x8*)(qbB + 32 + g * 8);

    f32x4 z = {0.f, 0.f, 0.f, 0.f};
    f32x4 oA[4], oB[4];
#pragma unroll
    for (int i = 0; i < 4; ++i) { oA[i] = z; oB[i] = z; }
    float lA = 0.f, lB = 0.f;

    // staging: thread (srow, sq) covers row srow, 16 elems at sq*16
    const int srow = tid >> 2, sq = tid & 3;
    const short* kg = kh + (size_t)(b * 1024 + srow) * 1024 + h * 64 + sq * 16;
    const short* vg = vT + ((size_t)(b * 16 + h)) * 65536 + (size_t)srow * 1024 + sq * 16;
    const int p0s = (sq * 2) ^ (srow & 7), p1s = (sq * 2 + 1) ^ (srow & 7);

    s16x8 kr0, kr1, vr0, vr1;
    auto stage_load = [&](int t) {
        const short* kp = kg + (size_t)(t * 64) * 1024;
        kr0 = *(const s16x8*)kp; kr1 = *(const s16x8*)(kp + 8);
        const short* vp = vg + t * 64;
        vr0 = *(const s16x8*)vp; vr1 = *(const s16x8*)(vp + 8);
    };
    auto stage_write = [&]() {
        char* kb2 = (char*)Ks;
        *(s16x8*)(kb2 + srow * 128 + p0s * 16) = kr0;
        *(s16x8*)(kb2 + srow * 128 + p1s * 16) = kr1;
        char* vb2 = (char*)Vs;
        *(s16x8*)(vb2 + srow * 128 + p0s * 16) = vr0;
        *(s16x8*)(vb2 + srow * 128 + p1s * 16) = vr1;
    };

    stage_load(0);
    for (int t = 0; t < 16; ++t) {
        if (t) __syncthreads();
        stage_write();
        __syncthreads();
        if (t < 15) stage_load(t + 1);   // issue next tile loads early

        // QK^T swapped; scores pre-scaled (exp2 domain); P = exp2(score + mask)
        f32x4 pA[4], pB[4];
        char* kb2 = (char*)Ks;
        float tsA = 0.f, tsB = 0.f;
#pragma unroll
        for (int fn = 0; fn < 4; ++fn) {
            int row = fn * 16 + r;
            s16x8 kfa = *(const s16x8*)(kb2 + row * 128 + ((g ^ (row & 7)) << 4));
            s16x8 kfb = *(const s16x8*)(kb2 + row * 128 + (((4 + g) ^ (row & 7)) << 4));
            f32x4 cA = __builtin_amdgcn_mfma_f32_16x16x32_bf16(kfa, qA0, z, 0, 0, 0);
            cA = __builtin_amdgcn_mfma_f32_16x16x32_bf16(kfb, qA1, cA, 0, 0, 0);
            f32x4 cB = __builtin_amdgcn_mfma_f32_16x16x32_bf16(kfa, qB0, z, 0, 0, 0);
            cB = __builtin_amdgcn_mfma_f32_16x16x32_bf16(kfb, qB1, cB, 0, 0, 0);
            f32x4 mv = *(const f32x4*)&mb[t * 64 + fn * 16 + g * 4];
#pragma unroll
            for (int qi = 0; qi < 4; ++qi) {
                float eA = vexp2(cA[qi] + mv[qi]); pA[fn][qi] = eA; tsA += eA;
                float eB = vexp2(cB[qi] + mv[qi]); pB[fn][qi] = eB; tsB += eB;
            }
        }
        tsA += __shfl_xor(tsA, 16); tsA += __shfl_xor(tsA, 32);
        tsB += __shfl_xor(tsB, 16); tsB += __shfl_xor(tsB, 32);
        lA += tsA; lB += tsB;

        // PV: pi-permuted V -> one b128 A-frag per (ks,df)
        char* vb2 = (char*)Vs;
#pragma unroll
        for (int ks = 0; ks < 2; ++ks) {
            s16x8 pbA = pack8(pA[2 * ks], pA[2 * ks + 1]);
            s16x8 pbB = pack8(pB[2 * ks], pB[2 * ks + 1]);
#pragma unroll
            for (int df = 0; df < 4; ++df) {
                int row = df * 16 + r;
                int slot = (ks * 4 + g) ^ (row & 7);
                s16x8 vf = *(const s16x8*)(vb2 + row * 128 + (slot << 4));
                oA[df] = __builtin_amdgcn_mfma_f32_16x16x32_bf16(vf, pbA, oA[df], 0, 0, 0);
                oB[df] = __builtin_amdgcn_mfma_f32_16x16x32_bf16(vf, pbB, oB[df], 0, 0, 0);
            }
        }
    }

    // epilogue
    float ivA = 1.f / lA, ivB = 1.f / lB;
#pragma unroll
    for (int df = 0; df < 4; ++df) {
        s16x4 oa, ob;
#pragma unroll
        for (int qi = 0; qi < 4; ++qi) {
            oa[qi] = f2b(oA[df][qi] * ivA);
            ob[qi] = f2b(oB[df][qi] * ivB);
        }
        *(s16x4*)&outp[(size_t)(b * 1024 + q0 + r) * 1024 + h * 64 + df * 16 + g * 4] = oa;
        *(s16x4*)&outp[(size_t)(b * 1024 + q0 + 16 + r) * 1024 + h * 64 + df * 16 + g * 4] = ob;
    }
}

// ---------------- launch ----------------
extern "C" void kernel_launch(void* const* d_in, const int* in_sizes, int n_in,
                              void* d_out, int out_size, void* d_ws, size_t ws_size,
                              hipStream_t stream) {
    const float* v  = (const float*)d_in[0];
    const float* k  = (const float*)d_in[1];
    const float* q  = (const float*)d_in[2];
    const float* rr = (const float*)d_in[3];
    const int* mask = (const int*)d_in[4];
    const float* Wv = (const float*)d_in[5];  const float* bv = (const float*)d_in[6];
    const float* Wk = (const float*)d_in[7];  const float* bk = (const float*)d_in[8];
    const float* Wq = (const float*)d_in[9];  const float* bq = (const float*)d_in[10];
    const float* Wr = (const float*)d_in[11]; const float* br = (const float*)d_in[12];
    const float* Wm = (const float*)d_in[13]; const float* bm = (const float*)d_in[14];

    const size_t MB = 1048576u;
    const size_t NEED = 90u * MB;   // W 10 + vb 16 + kb 16 + vtb 16 + khb 16 + qrb 16
    if (ws_size < NEED) return;     // leaves poison -> visible failure

    // Buffer lifetimes: vb,kb consumed by proj_all; att overwrites vb after.
    char* ws = (char*)d_ws;
    short* Wb  = (short*)ws;                  // 5 x 1M bf16
    short* vb  = (short*)(ws + 10u * MB);     // v bf16 (A for v-proj; later att)
    short* kb  = (short*)(ws + 26u * MB);     // k bf16
    short* vtb = (short*)(ws + 42u * MB);     // V^T [b][h][d][pos]
    short* khb = (short*)(ws + 58u * MB);     // K heads row-major
    short* qrb = (short*)(ws + 74u * MB);     // (q+r) heads, pre-scaled QSCL
    short* att = vb;                          // vb dead after proj_all

    Ptr7 t7;
    t7.p[0] = v;  t7.p[1] = k;
    t7.p[2] = Wv; t7.p[3] = Wk; t7.p[4] = Wq; t7.p[5] = Wr; t7.p[6] = Wm;
    cvt_all<<<dim3(10752), 256, 0, stream>>>(t7, vb, kb, Wb);

    proj_all<<<dim3(1536), 256, 0, stream>>>(vb, kb, q, rr, Wb,
                                             bv, bk, bq, br, vtb, khb, qrb);

    attn_fwd<<<dim3(128, 8), 256, 0, stream>>>(qrb, khb, vtb, mask, att);

    gemm_nt<0, 1, 0><<<dim3(512), 256, 0, stream>>>(att, nullptr, Wb + 4194304u,
                                                    nullptr, bm, nullptr, (float*)d_out);
}